// Round 6
// baseline (109.498 us; speedup 1.0000x reference)
//
#include <hip/hip_runtime.h>
#include <hip/hip_bf16.h>

#define NCLS 345
#define CPAD 384
#define DIM  512
#define BCAP 256

typedef float f32x4 __attribute__((ext_vector_type(4)));
typedef short s16x8 __attribute__((ext_vector_type(8)));
typedef short s16x4 __attribute__((ext_vector_type(4)));
typedef unsigned long long u64;

__device__ __forceinline__ short f2bf(float f) {
  union { float f; unsigned u; } v; v.f = f;
  unsigned r = v.u + 0x7fffu + ((v.u >> 16) & 1u);   // RNE
  return (short)(r >> 16);
}

// ---- Stage 1: one pass over N, bucket (ent_bits<<32)|idx per class ----
__global__ __launch_bounds__(256) void scan_classes(
    const float* __restrict__ ent, const int* __restrict__ y_hat,
    u64* __restrict__ bucket, int* __restrict__ cnt, int N)
{
  int i = blockIdx.x * 256 + threadIdx.x;
  if (i >= N) return;
  int c = y_hat[i];
  unsigned eb = __float_as_uint(ent[i]);
  u64 key = ((u64)eb << 32) | (unsigned)i;
  int p = atomicAdd(&cnt[c], 1);
  if (p < BCAP) bucket[(size_t)c * BCAP + p] = key;
}

// ---- Stage 2: per-class select (exact stable rank) + normalized-row sum ----
__global__ __launch_bounds__(512) void select_accum(
    const float* __restrict__ supports, const u64* __restrict__ bucket,
    const int* __restrict__ cnt, const int* __restrict__ fKp,
    short* __restrict__ Wt)
{
  const int c = blockIdx.x;
  const int tid = threadIdx.x;
  const int lane = tid & 63, w = tid >> 6;
  __shared__ u64   s_key[BCAP];
  __shared__ int   s_selidx[BCAP];
  __shared__ int   s_nsel;
  __shared__ float s_part[8][DIM];   // 16 KB
  __shared__ float s_red[8];
  if (tid == 0) s_nsel = 0;
  const int S = (c < NCLS) ? min(cnt[c], BCAP) : 0;
  const int K = fKp[0];
  for (int e = tid; e < S; e += 512) s_key[e] = bucket[(size_t)c * BCAP + e];
  __syncthreads();
  for (int e = tid; e < S; e += 512) {
    u64 ke = s_key[e];
    int r = 0;
    for (int j = 0; j < S; ++j) r += (s_key[j] < ke) ? 1 : 0;
    if (r < K) { int p = atomicAdd(&s_nsel, 1); s_selidx[p] = (int)(unsigned)(ke & 0xffffffffull); }
  }
  __syncthreads();
  const int nsel = s_nsel;
  f32x4 p0 = {0.f,0.f,0.f,0.f}, p1 = {0.f,0.f,0.f,0.f};
  for (int e0 = w; e0 < nsel; e0 += 16) {
    const int e1 = e0 + 8;
    const bool h1 = (e1 < nsel);
    const f32x4* r0 = (const f32x4*)(supports + (size_t)s_selidx[e0] * DIM);
    f32x4 a0 = r0[lane], a1 = r0[lane + 64];
    f32x4 b0 = {0.f,0.f,0.f,0.f}, b1 = {0.f,0.f,0.f,0.f};
    if (h1) {
      const f32x4* r1 = (const f32x4*)(supports + (size_t)s_selidx[e1] * DIM);
      b0 = r1[lane]; b1 = r1[lane + 64];
    }
    float s0 = 0.f, s1 = 0.f;
#pragma unroll
    for (int j = 0; j < 4; ++j) {
      s0 = fmaf(a0[j], a0[j], s0); s0 = fmaf(a1[j], a1[j], s0);
      s1 = fmaf(b0[j], b0[j], s1); s1 = fmaf(b1[j], b1[j], s1);
    }
#pragma unroll
    for (int off = 32; off; off >>= 1) { s0 += __shfl_xor(s0, off); s1 += __shfl_xor(s1, off); }
    float c0 = 1.f / fmaxf(sqrtf(s0), 1e-12f);
    float c1 = 1.f / fmaxf(sqrtf(s1), 1e-12f);
#pragma unroll
    for (int j = 0; j < 4; ++j) { p0[j] = fmaf(a0[j], c0, p0[j]); p1[j] = fmaf(a1[j], c0, p1[j]); }
    if (h1) {
#pragma unroll
      for (int j = 0; j < 4; ++j) { p0[j] = fmaf(b0[j], c1, p0[j]); p1[j] = fmaf(b1[j], c1, p1[j]); }
    }
  }
  *(f32x4*)&s_part[w][lane * 4]       = p0;
  *(f32x4*)&s_part[w][256 + lane * 4] = p1;
  __syncthreads();
  float acc = 0.f;
#pragma unroll
  for (int ww = 0; ww < 8; ++ww) acc += s_part[ww][tid];
  float sq = acc * acc;
#pragma unroll
  for (int off = 32; off; off >>= 1) sq += __shfl_xor(sq, off);
  if (lane == 0) s_red[w] = sq;
  __syncthreads();
  float tot = 0.f;
#pragma unroll
  for (int ww = 0; ww < 8; ++ww) tot += s_red[ww];
  float sc = 1.f / fmaxf(sqrtf(tot), 1e-12f);
  Wt[(size_t)c * DIM + tid] = f2bf(acc * sc);
}

// ---- Kernel B: out[M,345] = z[M,512] @ W ----
// BM=32 x BN=384 (z read once), BK=64, 8 waves each owning a disjoint 48-col
// group. B staged via global_load_lds width=16 (linear LDS dest, pre-swizzled
// global source). A: early f32x4 reg load -> cvt -> ds_write_b64. Epilogue:
// acc -> LDS C-blob (exact out layout) -> flat coalesced dwordx4 stores.
__global__ __launch_bounds__(512, 6) void gemm_zw(
    const float* __restrict__ z, const short* __restrict__ Wt,
    float* __restrict__ out)
{
  __shared__ __align__(16) char lds[53248];     // 4KB A + 48KB B; reused for C (44160B)
  char* const lA = lds;
  char* const lB = lds + 4096;
  const int tid  = threadIdx.x;
  const int lane = tid & 63;
  const int w    = tid >> 6;                    // wave 0..7 = col group
  const int bm   = blockIdx.x;
  const int fr   = lane & 15, fq = lane >> 4;
  const int Mbase = bm * 32;

  // A staging: thread -> row=tid>>4 (32 rows), seg=tid&15 (4 floats = 8B bf16)
  const int arow = tid >> 4, aseg = tid & 15;
  const float* gA = z + (size_t)(Mbase + arow) * DIM + aseg * 4;
  const unsigned aw = (unsigned)(arow * 128) + (((unsigned)(aseg * 8)) ^ (((unsigned)(arow & 7)) << 4));

  // B staging: wave w stages chunks w*6..w*6+5 (1KB each). Lane l of chunk c
  // fills LDS row r=c*8+(l>>3), slot s=l&7; source pre-swizzled: global slot s^(r&7).
  const int brow_off = lane >> 3, bslot = lane & 7;

  // fragment read offsets (XOR-swizzled)
  unsigned roA[2], roB[3];
#pragma unroll
  for (int mt = 0; mt < 2; ++mt) {
    int r = mt * 16 + fr;
    roA[mt] = (unsigned)(r * 128) + (((unsigned)(fq * 16)) ^ (((unsigned)(r & 7)) << 4));
  }
#pragma unroll
  for (int nt = 0; nt < 3; ++nt) {
    int r = w * 48 + nt * 16 + fr;
    roB[nt] = (unsigned)(r * 128) + (((unsigned)(fq * 16)) ^ (((unsigned)(r & 7)) << 4));
  }

  f32x4 acc[2][3];
#pragma unroll
  for (int mt = 0; mt < 2; ++mt)
#pragma unroll
    for (int nt = 0; nt < 3; ++nt) acc[mt][nt] = f32x4{0.f, 0.f, 0.f, 0.f};

#define STAGE_B(KT)                                                              \
  {                                                                              \
    _Pragma("unroll")                                                            \
    for (int i = 0; i < 6; ++i) {                                                \
      const int chunk = w * 6 + i;                                               \
      const int r = chunk * 8 + brow_off;                                        \
      const char* gsrc = (const char*)Wt + (size_t)r * (DIM * 2) + (KT) * 128    \
                         + ((bslot ^ (r & 7)) << 4);                             \
      __builtin_amdgcn_global_load_lds(                                          \
          (const __attribute__((address_space(1))) unsigned int*)gsrc,           \
          (__attribute__((address_space(3))) unsigned int*)(lB + chunk * 1024),  \
          16, 0, 0);                                                             \
    }                                                                            \
  }

#define WRITE_A(V)                                                               \
  {                                                                              \
    s16x4 a8;                                                                    \
    _Pragma("unroll")                                                            \
    for (int j = 0; j < 4; ++j) a8[j] = f2bf((V)[j]);                            \
    *(s16x4*)(lA + aw) = a8;                                                     \
  }

  // prologue: stage tile 0
  f32x4 av = *(const f32x4*)gA;
  STAGE_B(0);
  WRITE_A(av);
  __syncthreads();

#pragma unroll
  for (int kt = 0; kt < 8; ++kt) {
    f32x4 avn;
    if (kt < 7) avn = *(const f32x4*)(gA + (kt + 1) * 64);   // issue early
#pragma unroll
    for (int kk = 0; kk < 2; ++kk) {
      const unsigned kx = (unsigned)(kk << 6);
      s16x8 af[2], bf[3];
#pragma unroll
      for (int mt = 0; mt < 2; ++mt) af[mt] = *(const s16x8*)(lA + (roA[mt] ^ kx));
#pragma unroll
      for (int nt = 0; nt < 3; ++nt) bf[nt] = *(const s16x8*)(lB + (roB[nt] ^ kx));
#pragma unroll
      for (int nt = 0; nt < 3; ++nt)
#pragma unroll
        for (int mt = 0; mt < 2; ++mt)
          acc[mt][nt] = __builtin_amdgcn_mfma_f32_16x16x32_bf16(bf[nt], af[mt], acc[mt][nt], 0, 0, 0);
    }
    if (kt < 7) {
      __syncthreads();                 // all waves done reading this tile
      STAGE_B(kt + 1);
      WRITE_A(avn);
      __syncthreads();                 // staging complete (drains vm+lgkm)
    }
  }

  // ---- epilogue: acc -> LDS C blob (exact [32][345] f32 layout) ----
  __syncthreads();                      // safe to overwrite lds
#pragma unroll
  for (int mt = 0; mt < 2; ++mt) {
    const int row = mt * 16 + fr;
#pragma unroll
    for (int nt = 0; nt < 3; ++nt) {
      const int colb = w * 48 + nt * 16 + fq * 4;
#pragma unroll
      for (int j = 0; j < 4; ++j) {
        const int col = colb + j;
        if (col < NCLS) *(float*)(lds + (((size_t)row * NCLS + col) << 2)) = acc[mt][nt][j];
      }
    }
  }
  __syncthreads();
  // flat coalesced copy: 32*345*4 = 44160 B = 2760 x 16B
  char* dst = (char*)(out + (size_t)Mbase * NCLS);
  for (int c = tid; c < 2760; c += 512) {
    f32x4 v = *(const f32x4*)(lds + c * 16);
    *(f32x4*)(dst + c * 16) = v;
  }
#undef STAGE_B
#undef WRITE_A
}

extern "C" void kernel_launch(void* const* d_in, const int* in_sizes, int n_in,
                              void* d_out, int out_size, void* d_ws, size_t ws_size,
                              hipStream_t stream) {
  const float* z        = (const float*)d_in[0];
  const float* supports = (const float*)d_in[1];
  const float* ent      = (const float*)d_in[2];
  const int*   y_hat    = (const int*)d_in[3];
  const int*   fK       = (const int*)d_in[4];
  float* out = (float*)d_out;
  short* Wt  = (short*)d_ws;
  const int N = in_sizes[2];
  const int M = in_sizes[0] / DIM;

  const size_t offC = (size_t)CPAD * DIM * 2;          // 393216
  const size_t offB = offC + 2048;
  int* cnt    = (int*)((char*)d_ws + offC);
  u64* bucket = (u64*)((char*)d_ws + offB);
  hipMemsetAsync(cnt, 0, CPAD * sizeof(int), stream);
  scan_classes<<<dim3((N + 255) / 256), dim3(256), 0, stream>>>(ent, y_hat, bucket, cnt, N);
  select_accum<<<dim3(CPAD), dim3(512), 0, stream>>>(supports, bucket, cnt, fK, Wt);
  gemm_zw<<<dim3(M / 32), dim3(512), 0, stream>>>(z, Wt, out);
}